// Round 9
// baseline (213.427 us; speedup 1.0000x reference)
//
#include <hip/hip_runtime.h>
#include <stdint.h>

// Problem constants
#define T_TOK 16384     // 32*512 tokens
#define NE 8            // experts
#define EPSV 1e-8f
#define MAXC128 136     // max 128-token chunks: 128 + 7 partials, rounded up
#define MAXC64  264     // max 64-token chunks: 256 + 7 partials, rounded up

// ws layout (byte offsets).
#define WS_PERM   0                         // int[16384]
#define WS_PART   65536                     // int[64][8] per-block expert counts
#define WS_OFFS   67584                     // int[9]
#define WS_WT     131072                    // bf16[8][512][1024]  (W1|R1 transposed, B^T layout)
#define WS_H1     (WS_WT + 8*512*1024*2)    // bf16[16448][512] (64 slack rows)
#define WS_W2T    (WS_H1 + 16448*512*2)     // bf16[8][64][256]
#define WS_W3T    (WS_W2T + 8*64*256*2)     // bf16[8][32][64]
#define WS_W4T    (WS_W3T + 8*32*64*2)      // bf16[8][16][32]  (n>=14 zero)
#define WS_R2T    (WS_W4T + 8*16*32*2)      // bf16[8][16][256] (n>=3 zero)

typedef __attribute__((ext_vector_type(8))) short bf16x8;
typedef __attribute__((ext_vector_type(4))) float f32x4;

__device__ __forceinline__ unsigned short f2bf(float f) {
    unsigned u = __float_as_uint(f);
    u += 0x7fffu + ((u >> 16) & 1u);   // RNE
    return (unsigned short)(u >> 16);
}

// async global->LDS, 16B per lane. LDS dest = wave-uniform base + lane*16.
// LDS pointer converted via ADDRSPACECAST (pointer-type cast), never integer
// truncation (round-1 corruption root cause).
__device__ __forceinline__ void gl_lds16(const void* g, void* l) {
    __builtin_amdgcn_global_load_lds(
        (const __attribute__((address_space(1))) void*)g,
        (__attribute__((address_space(3))) void*)l,
        16, 0, 0);
}

// chunk id -> (expert, base, len) from the 9-entry prefix array. Uniform scalar loop.
__device__ __forceinline__ bool chunk_lookup(const int* __restrict__ offs, int c, int csize,
                                             int& e, int& base, int& len) {
    int acc = 0;
#pragma unroll
    for (int i = 0; i < NE; i++) {
        int s = offs[i], t = offs[i + 1];
        int cc = (t - s + csize - 1) / csize;
        if (c < acc + cc) {
            e = i;
            base = s + (c - acc) * csize;
            len = (t - base < csize) ? (t - base) : csize;
            return true;
        }
        acc += cc;
    }
    return false;
}

// ---------------- kernel 1: fused [W1|R1 transpose-convert + tail-weight convert | hist] ----
// blocks 0..1023: wcvt work (e = id>>7, ny = (id&127)>>4, kx = id&15)
// blocks 1024..1087: per-block expert histogram of sem
__global__ __launch_bounds__(256) void k_prep1(const float* __restrict__ W1,
                                               const float* __restrict__ R1,
                                               const float* __restrict__ W2,
                                               const float* __restrict__ W3,
                                               const float* __restrict__ W4,
                                               const float* __restrict__ R2,
                                               const int* __restrict__ sem,
                                               unsigned short* __restrict__ wt,
                                               unsigned short* __restrict__ w2t,
                                               unsigned short* __restrict__ w3t,
                                               unsigned short* __restrict__ w4t,
                                               unsigned short* __restrict__ r2t,
                                               int* __restrict__ ws_i) {
    __shared__ float tile[64][65];
    int id = blockIdx.x, tid = threadIdx.x;
    if (id >= 1024) {
        // ---- hist part ----
        __shared__ int cnt[NE];
        int hb = id - 1024, lane = tid & 63;
        if (tid < NE) cnt[tid] = 0;
        __syncthreads();
        int s = sem[hb * 256 + tid];
#pragma unroll
        for (int e = 0; e < NE; e++) {
            unsigned long long m = __ballot(s == e);
            if (lane == e) atomicAdd(&cnt[e], (int)__popcll(m));
        }
        __syncthreads();
        if (tid < NE) ws_i[(WS_PART >> 2) + hb * NE + tid] = cnt[tid];
        return;
    }
    // ---- wcvt part ----
    int e = id >> 7, rem = id & 127;
    int ny = rem >> 4, kx = rem & 15;
    int k0 = kx * 64, n0 = ny * 64;
    const float* src = (n0 < 256) ? (W1 + (size_t)e * 1024 * 256 + n0)
                                  : (R1 + (size_t)e * 1024 * 256 + (n0 - 256));
    int rr = tid >> 4;              // 0..15
    int cg = (tid & 15) * 4;
#pragma unroll
    for (int p = 0; p < 4; p++) {
        int kk = p * 16 + rr;
        float4 v = *(const float4*)(src + (size_t)(k0 + kk) * 256 + cg);
        tile[kk][cg] = v.x; tile[kk][cg + 1] = v.y; tile[kk][cg + 2] = v.z; tile[kk][cg + 3] = v.w;
    }
    __syncthreads();
    int nn = tid >> 3;              // 0..31
    int k8 = tid & 7;
#pragma unroll
    for (int p = 0; p < 2; p++) {
        int n = p * 32 + nn;
        unsigned w[4];
#pragma unroll
        for (int j = 0; j < 4; j++) {
            float f0 = tile[k8 * 8 + 2 * j][n];
            float f1 = tile[k8 * 8 + 2 * j + 1][n];
            w[j] = (unsigned)f2bf(f0) | ((unsigned)f2bf(f1) << 16);
        }
        *(uint4*)(wt + (size_t)(e * 512 + n0 + n) * 1024 + k0 + k8 * 8) =
            make_uint4(w[0], w[1], w[2], w[3]);
    }
    // tail-weight conversion on ny==0 blocks, sliced over kx (16 slices)
    if (ny == 0) {
        int x = kx;
        for (int j = tid; j < 1024; j += 256) {       // w2t: 16384/e -> 1024/slice
            int idx = x * 1024 + j; int k = idx & 255, n = idx >> 8;
            w2t[(size_t)(e * 64 + n) * 256 + k] = f2bf(W2[(size_t)e * 16384 + k * 64 + n]);
        }
        if (tid < 128) {                              // w3t: 2048/e -> 128/slice
            int idx = x * 128 + tid; int k = idx & 63, n = idx >> 6;
            w3t[(size_t)(e * 32 + n) * 64 + k] = f2bf(W3[(size_t)e * 2048 + k * 32 + n]);
        }
        if (tid < 32) {                               // w4t: 512/e -> 32/slice
            int idx = x * 32 + tid; int k = idx & 31, n = idx >> 5;
            w4t[(size_t)(e * 16 + n) * 32 + k] = (n < 14) ? f2bf(W4[(size_t)e * 448 + k * 14 + n])
                                                          : (unsigned short)0;
        }
        {                                             // r2t: 4096/e -> 256/slice
            int idx = x * 256 + tid; int k = idx & 255, n = idx >> 8;
            r2t[(size_t)(e * 16 + n) * 256 + k] = (n < 3) ? f2bf(R2[(size_t)e * 768 + k * 3 + n])
                                                          : (unsigned short)0;
        }
    }
}

// ---------------- kernel 2: scatter (deterministic, recomputes cursors from partials) ----
__global__ __launch_bounds__(256) void k_scatter(const int* __restrict__ sem, int* __restrict__ ws_i) {
    __shared__ int parts[64 * NE];
    __shared__ int tot[NE], preb[NE], ebase[NE + 1];
    __shared__ int cur[NE];
    int b = blockIdx.x, tid = threadIdx.x, lane = tid & 63;
    parts[tid] = ws_i[(WS_PART >> 2) + tid];
    parts[256 + tid] = ws_i[(WS_PART >> 2) + 256 + tid];
    __syncthreads();
    if (tid < NE) {
        int t = 0, p = 0;
        for (int bb = 0; bb < 64; bb++) {
            int v = parts[bb * NE + tid];
            t += v;
            if (bb < b) p += v;
        }
        tot[tid] = t; preb[tid] = p;
    }
    __syncthreads();
    if (tid == 0) {
        int base = 0;
        for (int e = 0; e < NE; e++) { ebase[e] = base; base += tot[e]; }
        ebase[NE] = base;
        if (b == 0)
            for (int e = 0; e <= NE; e++) ws_i[(WS_OFFS >> 2) + e] = ebase[e];
    }
    __syncthreads();
    if (tid < NE) cur[tid] = ebase[tid] + preb[tid];
    __syncthreads();
    int i = b * 256 + tid;
    int s = sem[i];
    int* perm = ws_i + (WS_PERM >> 2);
#pragma unroll
    for (int e = 0; e < NE; e++) {
        unsigned long long m = __ballot(s == e);
        if (s == e) {
            int leader = (int)__builtin_ctzll(m);
            int rank = (int)__popcll(m & ((1ull << lane) - 1ull));
            int bpos = 0;
            if (lane == leader) bpos = atomicAdd(&cur[e], (int)__popcll(m));
            bpos = __shfl(bpos, leader, 64);
            perm[bpos + rank] = i;
        }
    }
}

// ---------------- kernel 3: layer-1 GEMM with fused A-gather ----------------
// 128x128 tile, BK=64, swizzled LDS (slot (r,c) holds chunk c^(r&7), conflict-free R8-verified).
// A staged from nodes fp32 via perm (gather+convert+ds_write); B staged via global_load_lds.
__global__ __launch_bounds__(256) void k_gemm(const float* __restrict__ nodes,
                                              const unsigned short* __restrict__ wt,
                                              const float* __restrict__ b1,
                                              const float* __restrict__ rb1,
                                              const int* __restrict__ ws_i,
                                              unsigned short* __restrict__ h1) {
    __shared__ __align__(16) short As[128 * 64];   // 16 KB
    __shared__ __align__(16) short Bs[128 * 64];   // 16 KB
    int e, base, len;
    if (!chunk_lookup(ws_i + (WS_OFFS >> 2), blockIdx.x, 128, e, base, len)) return;
    int n0 = blockIdx.y * 128;
    int tid = threadIdx.x;
    int wave = tid >> 6, lane = tid & 63;
    int quad = lane >> 4, lr = lane & 15;
    int wm = (wave & 1) * 64, wn = (wave >> 1) * 64;
    const int* perm = ws_i + (WS_PERM >> 2);

    f32x4 acc[4][4];
#pragma unroll
    for (int i = 0; i < 4; i++)
#pragma unroll
        for (int j = 0; j < 4; j++) acc[i][j] = (f32x4){0.f, 0.f, 0.f, 0.f};

    const unsigned short* Bg = wt + (size_t)(e * 512 + n0) * 1024;

    // A gather sources: thread's 4 slots, rows R_i = i*32 + (tid>>3), chunk col c = tid&7,
    // swizzled cs = c ^ (R_i & 7) = (tid&7) ^ ((tid>>3)&7) (i*32 = 0 mod 8).
    int cs = (tid & 7) ^ ((tid >> 3) & 7);
    const float* srcA[4];
    const unsigned short* srcB[4];
    int dstA[4], dstB[4];
#pragma unroll
    for (int i = 0; i < 4; i++) {
        int R = i * 32 + (tid >> 3);
        int row = base + R; if (row > T_TOK - 1) row = T_TOK - 1;   // clamp: partial last chunk
        srcA[i] = nodes + (size_t)perm[row] * 1024 + cs * 8;
        dstA[i] = (i * 256 + tid) * 8;     // As slot s = R*8 + c
        // B staging (gl_lds): slot s = i*256 + wave*64 + lane, wave-uniform base
        int s = i * 256 + wave * 64 + lane;
        int r = s >> 3, cb = (s & 7) ^ (r & 7);
        srcB[i] = Bg + (size_t)r * 1024 + cb * 8;
        dstB[i] = (i * 256 + wave * 64) * 8;
    }

    for (int kb = 0; kb < 16; kb++) {
        __syncthreads();   // LDS safe to overwrite
#pragma unroll
        for (int i = 0; i < 4; i++)
            gl_lds16(srcB[i] + kb * 64, Bs + dstB[i]);
#pragma unroll
        for (int i = 0; i < 4; i++) {
            const float4* p = (const float4*)(srcA[i] + kb * 64);
            float4 a = p[0], b = p[1];
            unsigned r0 = (unsigned)f2bf(a.x) | ((unsigned)f2bf(a.y) << 16);
            unsigned r1 = (unsigned)f2bf(a.z) | ((unsigned)f2bf(a.w) << 16);
            unsigned r2 = (unsigned)f2bf(b.x) | ((unsigned)f2bf(b.y) << 16);
            unsigned r3 = (unsigned)f2bf(b.z) | ((unsigned)f2bf(b.w) << 16);
            *(uint4*)(As + dstA[i]) = make_uint4(r0, r1, r2, r3);
        }
        __syncthreads();   // drains lgkmcnt (ds_write) + vmcnt (gl_lds)

        bf16x8 af[2][4], bfr[2][4];
#pragma unroll
        for (int im = 0; im < 4; im++) {
            int r = wm + im * 16 + lr;
#pragma unroll
            for (int kh = 0; kh < 2; kh++) {
                int q = kh * 4 + quad;
                af[kh][im] = *(const bf16x8*)(As + (r * 8 + (q ^ (r & 7))) * 8);
            }
        }
#pragma unroll
        for (int in = 0; in < 4; in++) {
            int r = wn + in * 16 + lr;
#pragma unroll
            for (int kh = 0; kh < 2; kh++) {
                int q = kh * 4 + quad;
                bfr[kh][in] = *(const bf16x8*)(Bs + (r * 8 + (q ^ (r & 7))) * 8);
            }
        }
#pragma unroll
        for (int kh = 0; kh < 2; kh++)
#pragma unroll
            for (int im = 0; im < 4; im++)
#pragma unroll
                for (int in = 0; in < 4; in++)
                    acc[im][in] = __builtin_amdgcn_mfma_f32_16x16x32_bf16(af[kh][im], bfr[kh][in], acc[im][in], 0, 0, 0);
    }

    // epilogue: + bias, relu, store bf16. C/D layout: col=lane&15, row=quad*4+reg.
#pragma unroll
    for (int in = 0; in < 4; in++) {
        int gcol = n0 + wn + in * 16 + lr;
        float bias = (gcol < 256) ? b1[e * 256 + gcol] : rb1[e * 256 + gcol - 256];
#pragma unroll
        for (int im = 0; im < 4; im++) {
#pragma unroll
            for (int v = 0; v < 4; v++) {
                int r = wm + im * 16 + quad * 4 + v;
                if (r < len) {
                    float val = fmaxf(acc[im][in][v] + bias, 0.f);
                    h1[(size_t)(base + r) * 512 + gcol] = f2bf(val);
                }
            }
        }
    }
}

// ---------------- kernel 4: MFMA tail — layers 2-4 + rot + masked scatter ----------------
// 4 waves/block; wave w owns tokens [16w,16w+16) of its 64-token chunk. No barriers.
__global__ __launch_bounds__(256) void k_tail(const unsigned short* __restrict__ h1,
                                              const int* __restrict__ ws_i,
                                              const unsigned short* __restrict__ w2t,
                                              const unsigned short* __restrict__ w3t,
                                              const unsigned short* __restrict__ w4t,
                                              const unsigned short* __restrict__ r2t,
                                              const float* __restrict__ b2,
                                              const float* __restrict__ b3,
                                              const float* __restrict__ b4,
                                              const float* __restrict__ rb2,
                                              const int* __restrict__ lengths,
                                              float* __restrict__ out) {
    __shared__ __align__(16) unsigned short h2s[4][16][64];
    __shared__ __align__(16) unsigned short h3s[4][16][32];

    int e, base, len;
    if (!chunk_lookup(ws_i + (WS_OFFS >> 2), blockIdx.x, 64, e, base, len)) return;
    int tid = threadIdx.x, wave = tid >> 6, lane = tid & 63;
    int quad = lane >> 4, lr = lane & 15;
    int m0 = wave * 16;

    const unsigned short* Ap = h1 + (size_t)(base + m0) * 512;

    // layer2 (M=16,N=64,K=256) + rot (M=16,N=3pad16,K=256), A from global h1
    f32x4 acc2[4];
#pragma unroll
    for (int t = 0; t < 4; t++) {
        float bb = b2[e * 64 + t * 16 + lr];
        acc2[t] = (f32x4){bb, bb, bb, bb};
    }
    f32x4 accr;
    { float bb = (lr < 3) ? rb2[e * 3 + lr] : 0.f; accr = (f32x4){bb, bb, bb, bb}; }

    const unsigned short* W2e = w2t + (size_t)e * 64 * 256;
    const unsigned short* R2e = r2t + (size_t)e * 16 * 256;
#pragma unroll
    for (int kk = 0; kk < 8; kk++) {
        int k0 = kk * 32;
        bf16x8 a = *(const bf16x8*)(Ap + lr * 512 + k0 + quad * 8);
#pragma unroll
        for (int t = 0; t < 4; t++) {
            bf16x8 b = *(const bf16x8*)(W2e + (t * 16 + lr) * 256 + k0 + quad * 8);
            acc2[t] = __builtin_amdgcn_mfma_f32_16x16x32_bf16(a, b, acc2[t], 0, 0, 0);
        }
        bf16x8 ar = *(const bf16x8*)(Ap + lr * 512 + 256 + k0 + quad * 8);
        bf16x8 br = *(const bf16x8*)(R2e + lr * 256 + k0 + quad * 8);
        accr = __builtin_amdgcn_mfma_f32_16x16x32_bf16(ar, br, accr, 0, 0, 0);
    }
    // h2 = relu -> LDS bf16 (C layout: row=quad*4+v, col=lr per tile)
#pragma unroll
    for (int t = 0; t < 4; t++)
#pragma unroll
        for (int v = 0; v < 4; v++)
            h2s[wave][quad * 4 + v][t * 16 + lr] = f2bf(fmaxf(acc2[t][v], 0.f));

    // layer3 (M=16,N=32,K=64)
    f32x4 acc3[2];
#pragma unroll
    for (int t = 0; t < 2; t++) {
        float bb = b3[e * 32 + t * 16 + lr];
        acc3[t] = (f32x4){bb, bb, bb, bb};
    }
    const unsigned short* W3e = w3t + (size_t)e * 32 * 64;
#pragma unroll
    for (int kk = 0; kk < 2; kk++) {
        int k0 = kk * 32;
        bf16x8 a = *(const bf16x8*)(&h2s[wave][lr][k0 + quad * 8]);
#pragma unroll
        for (int t = 0; t < 2; t++) {
            bf16x8 b = *(const bf16x8*)(W3e + (t * 16 + lr) * 64 + k0 + quad * 8);
            acc3[t] = __builtin_amdgcn_mfma_f32_16x16x32_bf16(a, b, acc3[t], 0, 0, 0);
        }
    }
#pragma unroll
    for (int t = 0; t < 2; t++)
#pragma unroll
        for (int v = 0; v < 4; v++)
            h3s[wave][quad * 4 + v][t * 16 + lr] = f2bf(fmaxf(acc3[t][v], 0.f));

    // layer4 (M=16,N=14pad16,K=32): one MFMA
    f32x4 acc4;
    { float bb = (lr < 14) ? b4[e * 14 + lr] : 0.f; acc4 = (f32x4){bb, bb, bb, bb}; }
    {
        bf16x8 a = *(const bf16x8*)(&h3s[wave][lr][quad * 8]);
        bf16x8 b = *(const bf16x8*)(w4t + ((size_t)e * 16 + lr) * 32 + quad * 8);
        acc4 = __builtin_amdgcn_mfma_f32_16x16x32_bf16(a, b, acc4, 0, 0, 0);
    }

    // stores (masked): token row = quad*4+v
    const int* perm = ws_i + (WS_PERM >> 2);
#pragma unroll
    for (int v = 0; v < 4; v++) {
        int t = m0 + quad * 4 + v;
        if (t < len) {
            int token = perm[base + t];
            int bi = token >> 9, ni = token & 511;
            int valid = ni < lengths[bi];
            if (lr < 14) out[(size_t)token * 17 + lr] = valid ? acc4[v] : EPSV;
            if (lr < 3)  out[(size_t)token * 17 + 14 + lr] = valid ? accr[v] : EPSV;
        }
    }
}

extern "C" void kernel_launch(void* const* d_in, const int* in_sizes, int n_in,
                              void* d_out, int out_size, void* d_ws, size_t ws_size,
                              hipStream_t stream) {
    (void)in_sizes; (void)n_in; (void)out_size; (void)ws_size;
    const float* nodes   = (const float*)d_in[0];
    const int*   sem     = (const int*)d_in[1];
    const int*   lengths = (const int*)d_in[2];
    const float* W1 = (const float*)d_in[3];
    const float* b1 = (const float*)d_in[4];
    const float* W2 = (const float*)d_in[5];
    const float* b2 = (const float*)d_in[6];
    const float* W3 = (const float*)d_in[7];
    const float* b3 = (const float*)d_in[8];
    const float* W4 = (const float*)d_in[9];
    const float* b4 = (const float*)d_in[10];
    const float* R1  = (const float*)d_in[11];
    const float* rb1 = (const float*)d_in[12];
    const float* R2  = (const float*)d_in[13];
    const float* rb2 = (const float*)d_in[14];
    float* out = (float*)d_out;

    char* ws = (char*)d_ws;
    int* ws_i = (int*)ws;
    unsigned short* wt  = (unsigned short*)(ws + WS_WT);
    unsigned short* h1  = (unsigned short*)(ws + WS_H1);
    unsigned short* w2t = (unsigned short*)(ws + WS_W2T);
    unsigned short* w3t = (unsigned short*)(ws + WS_W3T);
    unsigned short* w4t = (unsigned short*)(ws + WS_W4T);
    unsigned short* r2t = (unsigned short*)(ws + WS_R2T);

    hipLaunchKernelGGL(k_prep1, dim3(1088), dim3(256), 0, stream,
                       W1, R1, W2, W3, W4, R2, sem, wt, w2t, w3t, w4t, r2t, ws_i);
    hipLaunchKernelGGL(k_scatter, dim3(64), dim3(256), 0, stream, sem, ws_i);
    hipLaunchKernelGGL(k_gemm, dim3(MAXC128, 4), dim3(256), 0, stream,
                       nodes, (const unsigned short*)wt, b1, rb1, (const int*)ws_i, h1);
    hipLaunchKernelGGL(k_tail, dim3(MAXC64), dim3(256), 0, stream,
                       (const unsigned short*)h1, (const int*)ws_i,
                       (const unsigned short*)w2t, (const unsigned short*)w3t,
                       (const unsigned short*)w4t, (const unsigned short*)r2t,
                       b2, b3, b4, rb2, lengths, out);
}

// Round 10
// 212.708 us; speedup vs baseline: 1.0034x; 1.0034x over previous
//
#include <hip/hip_runtime.h>
#include <stdint.h>

// Problem constants
#define T_TOK 16384     // 32*512 tokens
#define NE 8            // experts
#define EPSV 1e-8f
#define MAXC128 136     // max 128-token chunks
#define MAXC64  264     // max 64-token chunks

// ws layout (byte offsets).
#define WS_PERM   0                         // int[16384]
#define WS_PART   65536                     // int[64][8] per-block expert counts
#define WS_OFFS   67584                     // int[9]
#define WS_XSN    131072                    // bf16[16384][1024] natural token order
#define WS_WT     (WS_XSN + 16384*1024*2)   // bf16[8][512][1024]  (W1|R1 transposed, B^T layout)
#define WS_H1     (WS_WT + 8*512*1024*2)    // bf16[16448][512] (64 slack rows)
#define WS_W2T    (WS_H1 + 16448*512*2)     // bf16[8][64][256]
#define WS_W3T    (WS_W2T + 8*64*256*2)     // bf16[8][32][64]
#define WS_W4T    (WS_W3T + 8*32*64*2)      // bf16[8][16][32]  (n>=14 zero)
#define WS_R2T    (WS_W4T + 8*16*32*2)      // bf16[8][16][256] (n>=3 zero)

typedef __attribute__((ext_vector_type(8))) short bf16x8;
typedef __attribute__((ext_vector_type(4))) float f32x4;

__device__ __forceinline__ unsigned short f2bf(float f) {
    unsigned u = __float_as_uint(f);
    u += 0x7fffu + ((u >> 16) & 1u);   // RNE
    return (unsigned short)(u >> 16);
}

// async global->LDS, 16B per lane. LDS DEST = wave-uniform base + lane*16 (fixed);
// SOURCE is per-lane arbitrary (hardware gather). Addrspacecast only (round-1 lesson).
__device__ __forceinline__ void gl_lds16(const void* g, void* l) {
    __builtin_amdgcn_global_load_lds(
        (const __attribute__((address_space(1))) void*)g,
        (__attribute__((address_space(3))) void*)l,
        16, 0, 0);
}

// chunk id -> (expert, base, len) from the 9-entry prefix array. Uniform scalar loop.
__device__ __forceinline__ bool chunk_lookup(const int* __restrict__ offs, int c, int csize,
                                             int& e, int& base, int& len) {
    int acc = 0;
#pragma unroll
    for (int i = 0; i < NE; i++) {
        int s = offs[i], t = offs[i + 1];
        int cc = (t - s + csize - 1) / csize;
        if (c < acc + cc) {
            e = i;
            base = s + (c - acc) * csize;
            len = (t - base < csize) ? (t - base) : csize;
            return true;
        }
        acc += cc;
    }
    return false;
}

// ---------------- kernel 1: fused [wcvt | hist | xcvt] ----------------
// blocks 0..1023:    W1|R1 transpose-convert (+ tail-weight convert on ny==0)
// blocks 1024..1087: per-block expert histogram of sem
// blocks 1088..9279: nodes fp32 -> bf16, natural order (coalesced)
__global__ __launch_bounds__(256) void k_prep1(const float* __restrict__ W1,
                                               const float* __restrict__ R1,
                                               const float* __restrict__ W2,
                                               const float* __restrict__ W3,
                                               const float* __restrict__ W4,
                                               const float* __restrict__ R2,
                                               const float* __restrict__ nodes,
                                               const int* __restrict__ sem,
                                               unsigned short* __restrict__ wt,
                                               unsigned short* __restrict__ w2t,
                                               unsigned short* __restrict__ w3t,
                                               unsigned short* __restrict__ w4t,
                                               unsigned short* __restrict__ r2t,
                                               unsigned short* __restrict__ xsn,
                                               int* __restrict__ ws_i) {
    __shared__ float tile[64][65];
    int id = blockIdx.x, tid = threadIdx.x;
    if (id >= 1088) {
        // ---- xcvt: 8 consecutive elements per thread ----
        size_t gid = (size_t)(id - 1088) * 256 + tid;
        const float4* p = (const float4*)(nodes + gid * 8);
        float4 a = p[0], b = p[1];
        unsigned r0 = (unsigned)f2bf(a.x) | ((unsigned)f2bf(a.y) << 16);
        unsigned r1 = (unsigned)f2bf(a.z) | ((unsigned)f2bf(a.w) << 16);
        unsigned r2v = (unsigned)f2bf(b.x) | ((unsigned)f2bf(b.y) << 16);
        unsigned r3 = (unsigned)f2bf(b.z) | ((unsigned)f2bf(b.w) << 16);
        *(uint4*)(xsn + gid * 8) = make_uint4(r0, r1, r2v, r3);
        return;
    }
    if (id >= 1024) {
        // ---- hist ----
        __shared__ int cnt[NE];
        int hb = id - 1024, lane = tid & 63;
        if (tid < NE) cnt[tid] = 0;
        __syncthreads();
        int s = sem[hb * 256 + tid];
#pragma unroll
        for (int e = 0; e < NE; e++) {
            unsigned long long m = __ballot(s == e);
            if (lane == e) atomicAdd(&cnt[e], (int)__popcll(m));
        }
        __syncthreads();
        if (tid < NE) ws_i[(WS_PART >> 2) + hb * NE + tid] = cnt[tid];
        return;
    }
    // ---- wcvt ----
    int e = id >> 7, rem = id & 127;
    int ny = rem >> 4, kx = rem & 15;
    int k0 = kx * 64, n0 = ny * 64;
    const float* src = (n0 < 256) ? (W1 + (size_t)e * 1024 * 256 + n0)
                                  : (R1 + (size_t)e * 1024 * 256 + (n0 - 256));
    int rr = tid >> 4;              // 0..15
    int cg = (tid & 15) * 4;
#pragma unroll
    for (int p = 0; p < 4; p++) {
        int kk = p * 16 + rr;
        float4 v = *(const float4*)(src + (size_t)(k0 + kk) * 256 + cg);
        tile[kk][cg] = v.x; tile[kk][cg + 1] = v.y; tile[kk][cg + 2] = v.z; tile[kk][cg + 3] = v.w;
    }
    __syncthreads();
    int nn = tid >> 3;              // 0..31
    int k8 = tid & 7;
#pragma unroll
    for (int p = 0; p < 2; p++) {
        int n = p * 32 + nn;
        unsigned w[4];
#pragma unroll
        for (int j = 0; j < 4; j++) {
            float f0 = tile[k8 * 8 + 2 * j][n];
            float f1 = tile[k8 * 8 + 2 * j + 1][n];
            w[j] = (unsigned)f2bf(f0) | ((unsigned)f2bf(f1) << 16);
        }
        *(uint4*)(wt + (size_t)(e * 512 + n0 + n) * 1024 + k0 + k8 * 8) =
            make_uint4(w[0], w[1], w[2], w[3]);
    }
    // tail-weight conversion on ny==0 blocks, sliced over kx (16 slices)
    if (ny == 0) {
        int x = kx;
        for (int j = tid; j < 1024; j += 256) {
            int idx = x * 1024 + j; int k = idx & 255, n = idx >> 8;
            w2t[(size_t)(e * 64 + n) * 256 + k] = f2bf(W2[(size_t)e * 16384 + k * 64 + n]);
        }
        if (tid < 128) {
            int idx = x * 128 + tid; int k = idx & 63, n = idx >> 6;
            w3t[(size_t)(e * 32 + n) * 64 + k] = f2bf(W3[(size_t)e * 2048 + k * 32 + n]);
        }
        if (tid < 32) {
            int idx = x * 32 + tid; int k = idx & 31, n = idx >> 5;
            w4t[(size_t)(e * 16 + n) * 32 + k] = (n < 14) ? f2bf(W4[(size_t)e * 448 + k * 14 + n])
                                                          : (unsigned short)0;
        }
        {
            int idx = x * 256 + tid; int k = idx & 255, n = idx >> 8;
            r2t[(size_t)(e * 16 + n) * 256 + k] = (n < 3) ? f2bf(R2[(size_t)e * 768 + k * 3 + n])
                                                          : (unsigned short)0;
        }
    }
}

// ---------------- kernel 2: scatter (deterministic, recomputes cursors from partials) ----
__global__ __launch_bounds__(256) void k_scatter(const int* __restrict__ sem, int* __restrict__ ws_i) {
    __shared__ int parts[64 * NE];
    __shared__ int tot[NE], preb[NE], ebase[NE + 1];
    __shared__ int cur[NE];
    int b = blockIdx.x, tid = threadIdx.x, lane = tid & 63;
    parts[tid] = ws_i[(WS_PART >> 2) + tid];
    parts[256 + tid] = ws_i[(WS_PART >> 2) + 256 + tid];
    __syncthreads();
    if (tid < NE) {
        int t = 0, p = 0;
        for (int bb = 0; bb < 64; bb++) {
            int v = parts[bb * NE + tid];
            t += v;
            if (bb < b) p += v;
        }
        tot[tid] = t; preb[tid] = p;
    }
    __syncthreads();
    if (tid == 0) {
        int base = 0;
        for (int e = 0; e < NE; e++) { ebase[e] = base; base += tot[e]; }
        ebase[NE] = base;
        if (b == 0)
            for (int e = 0; e <= NE; e++) ws_i[(WS_OFFS >> 2) + e] = ebase[e];
    }
    __syncthreads();
    if (tid < NE) cur[tid] = ebase[tid] + preb[tid];
    __syncthreads();
    int i = b * 256 + tid;
    int s = sem[i];
    int* perm = ws_i + (WS_PERM >> 2);
#pragma unroll
    for (int e = 0; e < NE; e++) {
        unsigned long long m = __ballot(s == e);
        if (s == e) {
            int leader = (int)__builtin_ctzll(m);
            int rank = (int)__popcll(m & ((1ull << lane) - 1ull));
            int bpos = 0;
            if (lane == leader) bpos = atomicAdd(&cur[e], (int)__popcll(m));
            bpos = __shfl(bpos, leader, 64);
            perm[bpos + rank] = i;
        }
    }
}

// ---------------- kernel 3: layer-1 GEMM, A gathered via global_load_lds ----------------
// 128x128 tile, BK=64, XOR-swizzled LDS (R8-verified, 0 conflicts). A staged by gl_lds
// with per-lane GATHERED sources from natural-order xsn via perm — keeps the R8 async
// pipeline (R9's VGPR round-trip was the regression). Each 8-lane row-group fetches one
// contiguous 128B line (swizzle permutes within the line).
__global__ __launch_bounds__(256) void k_gemm(const unsigned short* __restrict__ xsn,
                                              const unsigned short* __restrict__ wt,
                                              const float* __restrict__ b1,
                                              const float* __restrict__ rb1,
                                              const int* __restrict__ ws_i,
                                              unsigned short* __restrict__ h1) {
    __shared__ __align__(16) short As[128 * 64];   // 16 KB
    __shared__ __align__(16) short Bs[128 * 64];   // 16 KB
    int e, base, len;
    if (!chunk_lookup(ws_i + (WS_OFFS >> 2), blockIdx.x, 128, e, base, len)) return;
    int n0 = blockIdx.y * 128;
    int tid = threadIdx.x;
    int wave = tid >> 6, lane = tid & 63;
    int quad = lane >> 4, lr = lane & 15;
    int wm = (wave & 1) * 64, wn = (wave >> 1) * 64;
    const int* perm = ws_i + (WS_PERM >> 2);

    f32x4 acc[4][4];
#pragma unroll
    for (int i = 0; i < 4; i++)
#pragma unroll
        for (int j = 0; j < 4; j++) acc[i][j] = (f32x4){0.f, 0.f, 0.f, 0.f};

    const unsigned short* Bg = wt + (size_t)(e * 512 + n0) * 1024;

    // per-thread staging sources. Slot s = i*256 + wave*64 + lane; row r = s>>3;
    // swizzled chunk cs = (s&7)^(r&7) = (lane&7)^((lane>>3)&7) (i,wave are 0 mod 8 in r).
    int cs = (lane & 7) ^ ((lane >> 3) & 7);
    const unsigned short* srcA[4];
    const unsigned short* srcB[4];
    int dstA[4], dstB[4];
#pragma unroll
    for (int i = 0; i < 4; i++) {
        int r = i * 32 + wave * 8 + (lane >> 3);
        int row = base + r; if (row > T_TOK - 1) row = T_TOK - 1;  // clamp partial chunk
        srcA[i] = xsn + (size_t)perm[row] * 1024 + cs * 8;          // gathered source
        dstA[i] = (i * 256 + wave * 64) * 8;                        // wave-uniform dest
        srcB[i] = Bg + (size_t)r * 1024 + cs * 8;
        dstB[i] = (i * 256 + wave * 64) * 8;
    }

    for (int kb = 0; kb < 16; kb++) {
        __syncthreads();   // LDS safe to overwrite
#pragma unroll
        for (int i = 0; i < 4; i++) {
            gl_lds16(srcA[i] + kb * 64, As + dstA[i]);
            gl_lds16(srcB[i] + kb * 64, Bs + dstB[i]);
        }
        __syncthreads();   // vmcnt(0) drain: DMA complete

        bf16x8 af[2][4], bfr[2][4];
#pragma unroll
        for (int im = 0; im < 4; im++) {
            int r = wm + im * 16 + lr;
#pragma unroll
            for (int kh = 0; kh < 2; kh++) {
                int q = kh * 4 + quad;
                af[kh][im] = *(const bf16x8*)(As + (r * 8 + (q ^ (r & 7))) * 8);
            }
        }
#pragma unroll
        for (int in = 0; in < 4; in++) {
            int r = wn + in * 16 + lr;
#pragma unroll
            for (int kh = 0; kh < 2; kh++) {
                int q = kh * 4 + quad;
                bfr[kh][in] = *(const bf16x8*)(Bs + (r * 8 + (q ^ (r & 7))) * 8);
            }
        }
#pragma unroll
        for (int kh = 0; kh < 2; kh++)
#pragma unroll
            for (int im = 0; im < 4; im++)
#pragma unroll
                for (int in = 0; in < 4; in++)
                    acc[im][in] = __builtin_amdgcn_mfma_f32_16x16x32_bf16(af[kh][im], bfr[kh][in], acc[im][in], 0, 0, 0);
    }

    // epilogue: + bias, relu, store bf16. C/D layout: col=lane&15, row=quad*4+reg.
#pragma unroll
    for (int in = 0; in < 4; in++) {
        int gcol = n0 + wn + in * 16 + lr;
        float bias = (gcol < 256) ? b1[e * 256 + gcol] : rb1[e * 256 + gcol - 256];
#pragma unroll
        for (int im = 0; im < 4; im++) {
#pragma unroll
            for (int v = 0; v < 4; v++) {
                int r = wm + im * 16 + quad * 4 + v;
                if (r < len) {
                    float val = fmaxf(acc[im][in][v] + bias, 0.f);
                    h1[(size_t)(base + r) * 512 + gcol] = f2bf(val);
                }
            }
        }
    }
}

// ---------------- kernel 4: MFMA tail — layers 2-4 + rot + masked scatter ----------------
__global__ __launch_bounds__(256) void k_tail(const unsigned short* __restrict__ h1,
                                              const int* __restrict__ ws_i,
                                              const unsigned short* __restrict__ w2t,
                                              const unsigned short* __restrict__ w3t,
                                              const unsigned short* __restrict__ w4t,
                                              const unsigned short* __restrict__ r2t,
                                              const float* __restrict__ b2,
                                              const float* __restrict__ b3,
                                              const float* __restrict__ b4,
                                              const float* __restrict__ rb2,
                                              const int* __restrict__ lengths,
                                              float* __restrict__ out) {
    __shared__ __align__(16) unsigned short h2s[4][16][64];
    __shared__ __align__(16) unsigned short h3s[4][16][32];

    int e, base, len;
    if (!chunk_lookup(ws_i + (WS_OFFS >> 2), blockIdx.x, 64, e, base, len)) return;
    int tid = threadIdx.x, wave = tid >> 6, lane = tid & 63;
    int quad = lane >> 4, lr = lane & 15;
    int m0 = wave * 16;

    const unsigned short* Ap = h1 + (size_t)(base + m0) * 512;

    f32x4 acc2[4];
#pragma unroll
    for (int t = 0; t < 4; t++) {
        float bb = b2[e * 64 + t * 16 + lr];
        acc2[t] = (f32x4){bb, bb, bb, bb};
    }
    f32x4 accr;
    { float bb = (lr < 3) ? rb2[e * 3 + lr] : 0.f; accr = (f32x4){bb, bb, bb, bb}; }

    const unsigned short* W2e = w2t + (size_t)e * 64 * 256;
    const unsigned short* R2e = r2t + (size_t)e * 16 * 256;
#pragma unroll
    for (int kk = 0; kk < 8; kk++) {
        int k0 = kk * 32;
        bf16x8 a = *(const bf16x8*)(Ap + lr * 512 + k0 + quad * 8);
#pragma unroll
        for (int t = 0; t < 4; t++) {
            bf16x8 b = *(const bf16x8*)(W2e + (t * 16 + lr) * 256 + k0 + quad * 8);
            acc2[t] = __builtin_amdgcn_mfma_f32_16x16x32_bf16(a, b, acc2[t], 0, 0, 0);
        }
        bf16x8 ar = *(const bf16x8*)(Ap + lr * 512 + 256 + k0 + quad * 8);
        bf16x8 br = *(const bf16x8*)(R2e + lr * 256 + k0 + quad * 8);
        accr = __builtin_amdgcn_mfma_f32_16x16x32_bf16(ar, br, accr, 0, 0, 0);
    }
#pragma unroll
    for (int t = 0; t < 4; t++)
#pragma unroll
        for (int v = 0; v < 4; v++)
            h2s[wave][quad * 4 + v][t * 16 + lr] = f2bf(fmaxf(acc2[t][v], 0.f));

    f32x4 acc3[2];
#pragma unroll
    for (int t = 0; t < 2; t++) {
        float bb = b3[e * 32 + t * 16 + lr];
        acc3[t] = (f32x4){bb, bb, bb, bb};
    }
    const unsigned short* W3e = w3t + (size_t)e * 32 * 64;
#pragma unroll
    for (int kk = 0; kk < 2; kk++) {
        int k0 = kk * 32;
        bf16x8 a = *(const bf16x8*)(&h2s[wave][lr][k0 + quad * 8]);
#pragma unroll
        for (int t = 0; t < 2; t++) {
            bf16x8 b = *(const bf16x8*)(W3e + (t * 16 + lr) * 64 + k0 + quad * 8);
            acc3[t] = __builtin_amdgcn_mfma_f32_16x16x32_bf16(a, b, acc3[t], 0, 0, 0);
        }
    }
#pragma unroll
    for (int t = 0; t < 2; t++)
#pragma unroll
        for (int v = 0; v < 4; v++)
            h3s[wave][quad * 4 + v][t * 16 + lr] = f2bf(fmaxf(acc3[t][v], 0.f));

    f32x4 acc4;
    { float bb = (lr < 14) ? b4[e * 14 + lr] : 0.f; acc4 = (f32x4){bb, bb, bb, bb}; }
    {
        bf16x8 a = *(const bf16x8*)(&h3s[wave][lr][quad * 8]);
        bf16x8 b = *(const bf16x8*)(w4t + ((size_t)e * 16 + lr) * 32 + quad * 8);
        acc4 = __builtin_amdgcn_mfma_f32_16x16x32_bf16(a, b, acc4, 0, 0, 0);
    }

    const int* perm = ws_i + (WS_PERM >> 2);
#pragma unroll
    for (int v = 0; v < 4; v++) {
        int t = m0 + quad * 4 + v;
        if (t < len) {
            int token = perm[base + t];
            int bi = token >> 9, ni = token & 511;
            int valid = ni < lengths[bi];
            if (lr < 14) out[(size_t)token * 17 + lr] = valid ? acc4[v] : EPSV;
            if (lr < 3)  out[(size_t)token * 17 + 14 + lr] = valid ? accr[v] : EPSV;
        }
    }
}

extern "C" void kernel_launch(void* const* d_in, const int* in_sizes, int n_in,
                              void* d_out, int out_size, void* d_ws, size_t ws_size,
                              hipStream_t stream) {
    (void)in_sizes; (void)n_in; (void)out_size; (void)ws_size;
    const float* nodes   = (const float*)d_in[0];
    const int*   sem     = (const int*)d_in[1];
    const int*   lengths = (const int*)d_in[2];
    const float* W1 = (const float*)d_in[3];
    const float* b1 = (const float*)d_in[4];
    const float* W2 = (const float*)d_in[5];
    const float* b2 = (const float*)d_in[6];
    const float* W3 = (const float*)d_in[7];
    const float* b3 = (const float*)d_in[8];
    const float* W4 = (const float*)d_in[9];
    const float* b4 = (const float*)d_in[10];
    const float* R1  = (const float*)d_in[11];
    const float* rb1 = (const float*)d_in[12];
    const float* R2  = (const float*)d_in[13];
    const float* rb2 = (const float*)d_in[14];
    float* out = (float*)d_out;

    char* ws = (char*)d_ws;
    int* ws_i = (int*)ws;
    unsigned short* xsn = (unsigned short*)(ws + WS_XSN);
    unsigned short* wt  = (unsigned short*)(ws + WS_WT);
    unsigned short* h1  = (unsigned short*)(ws + WS_H1);
    unsigned short* w2t = (unsigned short*)(ws + WS_W2T);
    unsigned short* w3t = (unsigned short*)(ws + WS_W3T);
    unsigned short* w4t = (unsigned short*)(ws + WS_W4T);
    unsigned short* r2t = (unsigned short*)(ws + WS_R2T);

    hipLaunchKernelGGL(k_prep1, dim3(9280), dim3(256), 0, stream,
                       W1, R1, W2, W3, W4, R2, nodes, sem,
                       wt, w2t, w3t, w4t, r2t, xsn, ws_i);
    hipLaunchKernelGGL(k_scatter, dim3(64), dim3(256), 0, stream, sem, ws_i);
    hipLaunchKernelGGL(k_gemm, dim3(MAXC128, 4), dim3(256), 0, stream,
                       (const unsigned short*)xsn, (const unsigned short*)wt, b1, rb1,
                       (const int*)ws_i, h1);
    hipLaunchKernelGGL(k_tail, dim3(MAXC64), dim3(256), 0, stream,
                       (const unsigned short*)h1, (const int*)ws_i,
                       (const unsigned short*)w2t, (const unsigned short*)w3t,
                       (const unsigned short*)w4t, (const unsigned short*)r2t,
                       b2, b3, b4, rb2, lengths, out);
}

// Round 11
// 198.672 us; speedup vs baseline: 1.0743x; 1.0706x over previous
//
#include <hip/hip_runtime.h>
#include <stdint.h>

// Problem constants
#define T_TOK 16384     // 32*512 tokens
#define NE 8            // experts
#define EPSV 1e-8f
#define MAXC128 136     // max 128-token chunks
#define MAXC64  264     // max 64-token chunks

// ws layout (byte offsets). Total ~56.8 MiB.
#define WS_PERM   0                         // int[16384]
#define WS_PART   65536                     // int[64][8] per-block expert counts
#define WS_OFFS   67584                     // int[9]
#define WS_XS     131072                    // bf16[16512][1024] sorted (128 slack rows)
#define WS_WT     (WS_XS + 16512*1024*2)    // bf16[8][512][1024]  (W1|R1 transposed, B^T layout)
#define WS_H1     (WS_WT + 8*512*1024*2)    // bf16[16448][512] (64 slack rows)
#define WS_W2T    (WS_H1 + 16448*512*2)     // bf16[8][64][256]
#define WS_W3T    (WS_W2T + 8*64*256*2)     // bf16[8][32][64]
#define WS_W4T    (WS_W3T + 8*32*64*2)      // bf16[8][16][32]  (n>=14 zero)
#define WS_R2T    (WS_W4T + 8*16*32*2)      // bf16[8][16][256] (n>=3 zero)

typedef __attribute__((ext_vector_type(8))) short bf16x8;
typedef __attribute__((ext_vector_type(4))) float f32x4;

__device__ __forceinline__ unsigned short f2bf(float f) {
    unsigned u = __float_as_uint(f);
    u += 0x7fffu + ((u >> 16) & 1u);   // RNE
    return (unsigned short)(u >> 16);
}

// async global->LDS, 16B per lane. LDS DEST = wave-uniform base + lane*16.
// Addrspacecast only (round-1 lesson: integer truncation of generic LDS ptr = garbage).
__device__ __forceinline__ void gl_lds16(const void* g, void* l) {
    __builtin_amdgcn_global_load_lds(
        (const __attribute__((address_space(1))) void*)g,
        (__attribute__((address_space(3))) void*)l,
        16, 0, 0);
}

// chunk id -> (expert, base, len) from the 9-entry prefix array. Uniform scalar loop.
__device__ __forceinline__ bool chunk_lookup(const int* __restrict__ offs, int c, int csize,
                                             int& e, int& base, int& len) {
    int acc = 0;
#pragma unroll
    for (int i = 0; i < NE; i++) {
        int s = offs[i], t = offs[i + 1];
        int cc = (t - s + csize - 1) / csize;
        if (c < acc + cc) {
            e = i;
            base = s + (c - acc) * csize;
            len = (t - base < csize) ? (t - base) : csize;
            return true;
        }
        acc += cc;
    }
    return false;
}

// ---------------- kernel 1: fused [wcvt | hist] ----------------
// blocks 0..1023:    W1|R1 transpose-convert (+ tail-weight convert on ny==0)
// blocks 1024..1087: per-block expert histogram of sem
__global__ __launch_bounds__(256) void k_prep1(const float* __restrict__ W1,
                                               const float* __restrict__ R1,
                                               const float* __restrict__ W2,
                                               const float* __restrict__ W3,
                                               const float* __restrict__ W4,
                                               const float* __restrict__ R2,
                                               const int* __restrict__ sem,
                                               unsigned short* __restrict__ wt,
                                               unsigned short* __restrict__ w2t,
                                               unsigned short* __restrict__ w3t,
                                               unsigned short* __restrict__ w4t,
                                               unsigned short* __restrict__ r2t,
                                               int* __restrict__ ws_i) {
    __shared__ float tile[64][65];
    int id = blockIdx.x, tid = threadIdx.x;
    if (id >= 1024) {
        __shared__ int cnt[NE];
        int hb = id - 1024, lane = tid & 63;
        if (tid < NE) cnt[tid] = 0;
        __syncthreads();
        int s = sem[hb * 256 + tid];
#pragma unroll
        for (int e = 0; e < NE; e++) {
            unsigned long long m = __ballot(s == e);
            if (lane == e) atomicAdd(&cnt[e], (int)__popcll(m));
        }
        __syncthreads();
        if (tid < NE) ws_i[(WS_PART >> 2) + hb * NE + tid] = cnt[tid];
        return;
    }
    int e = id >> 7, rem = id & 127;
    int ny = rem >> 4, kx = rem & 15;
    int k0 = kx * 64, n0 = ny * 64;
    const float* src = (n0 < 256) ? (W1 + (size_t)e * 1024 * 256 + n0)
                                  : (R1 + (size_t)e * 1024 * 256 + (n0 - 256));
    int rr = tid >> 4;
    int cg = (tid & 15) * 4;
#pragma unroll
    for (int p = 0; p < 4; p++) {
        int kk = p * 16 + rr;
        float4 v = *(const float4*)(src + (size_t)(k0 + kk) * 256 + cg);
        tile[kk][cg] = v.x; tile[kk][cg + 1] = v.y; tile[kk][cg + 2] = v.z; tile[kk][cg + 3] = v.w;
    }
    __syncthreads();
    int nn = tid >> 3;
    int k8 = tid & 7;
#pragma unroll
    for (int p = 0; p < 2; p++) {
        int n = p * 32 + nn;
        unsigned w[4];
#pragma unroll
        for (int j = 0; j < 4; j++) {
            float f0 = tile[k8 * 8 + 2 * j][n];
            float f1 = tile[k8 * 8 + 2 * j + 1][n];
            w[j] = (unsigned)f2bf(f0) | ((unsigned)f2bf(f1) << 16);
        }
        *(uint4*)(wt + (size_t)(e * 512 + n0 + n) * 1024 + k0 + k8 * 8) =
            make_uint4(w[0], w[1], w[2], w[3]);
    }
    if (ny == 0) {
        int x = kx;
        for (int j = tid; j < 1024; j += 256) {
            int idx = x * 1024 + j; int k = idx & 255, n = idx >> 8;
            w2t[(size_t)(e * 64 + n) * 256 + k] = f2bf(W2[(size_t)e * 16384 + k * 64 + n]);
        }
        if (tid < 128) {
            int idx = x * 128 + tid; int k = idx & 63, n = idx >> 6;
            w3t[(size_t)(e * 32 + n) * 64 + k] = f2bf(W3[(size_t)e * 2048 + k * 32 + n]);
        }
        if (tid < 32) {
            int idx = x * 32 + tid; int k = idx & 31, n = idx >> 5;
            w4t[(size_t)(e * 16 + n) * 32 + k] = (n < 14) ? f2bf(W4[(size_t)e * 448 + k * 14 + n])
                                                          : (unsigned short)0;
        }
        {
            int idx = x * 256 + tid; int k = idx & 255, n = idx >> 8;
            r2t[(size_t)(e * 16 + n) * 256 + k] = (n < 3) ? f2bf(R2[(size_t)e * 768 + k * 3 + n])
                                                          : (unsigned short)0;
        }
    }
}

// ---------------- kernel 2: scatter + sorted gather-convert ----------------
// 512 blocks = 8 siblings per 256-token group g. Each sibling DETERMINISTICALLY
// recomputes dest[] for group g (ballot + per-wave prefix, NO atomics — siblings must
// agree), then copies its 32-row slice of nodes fp32 -> sorted bf16 xs (coalesced).
// Sibling j==0 additionally writes perm and (g==0) the offs table.
__global__ __launch_bounds__(256) void k_scatter(const int* __restrict__ sem,
                                                 const float* __restrict__ nodes,
                                                 int* __restrict__ ws_i,
                                                 unsigned short* __restrict__ xs) {
    __shared__ int parts[512];
    __shared__ int tot[NE], preb[NE], ebase[NE + 1];
    __shared__ int wcnt[4][NE];
    __shared__ int destS[256];
    int b = blockIdx.x, g = b >> 3, j = b & 7;
    int tid = threadIdx.x, wave = tid >> 6, lane = tid & 63;
    parts[tid] = ws_i[(WS_PART >> 2) + tid];
    parts[256 + tid] = ws_i[(WS_PART >> 2) + 256 + tid];
    __syncthreads();
    if (tid < NE) {
        int t = 0, p = 0;
        for (int bb = 0; bb < 64; bb++) {
            int v = parts[bb * NE + tid];
            t += v;
            if (bb < g) p += v;
        }
        tot[tid] = t; preb[tid] = p;
    }
    __syncthreads();
    if (tid == 0) {
        int base = 0;
        for (int e = 0; e < NE; e++) { ebase[e] = base; base += tot[e]; }
        ebase[NE] = base;
        if (b == 0)
            for (int e = 0; e <= NE; e++) ws_i[(WS_OFFS >> 2) + e] = ebase[e];
    }
    int i = g * 256 + tid;
    int s = sem[i];
    int rank = 0;
#pragma unroll
    for (int e = 0; e < NE; e++) {
        unsigned long long m = __ballot(s == e);
        if (s == e) rank = (int)__popcll(m & ((1ull << lane) - 1ull));
        if (lane == e) wcnt[wave][e] = (int)__popcll(m);
    }
    __syncthreads();
    int wpre = 0;
#pragma unroll
    for (int w = 0; w < 4; w++)
        if (w < wave) wpre += wcnt[w][s];
    int dest = ebase[s] + preb[s] + wpre + rank;
    destS[tid] = dest;
    if (j == 0) ws_i[(WS_PERM >> 2) + dest] = i;
    __syncthreads();
    // copy slice: rows r = j*32 .. j*32+31; each thread converts 4 floats/row
#pragma unroll 4
    for (int r = j * 32; r < j * 32 + 32; r++) {
        int tok = g * 256 + r;
        int d = destS[r];
        float4 v = *(const float4*)(nodes + (size_t)tok * 1024 + tid * 4);
        unsigned p0 = (unsigned)f2bf(v.x) | ((unsigned)f2bf(v.y) << 16);
        unsigned p1 = (unsigned)f2bf(v.z) | ((unsigned)f2bf(v.w) << 16);
        *(uint2*)(xs + (size_t)d * 1024 + tid * 4) = make_uint2(p0, p1);
    }
}

// ---------------- kernel 3: layer-1 GEMM (R8-verified: 44.5us, 0 conflicts) ----------------
// 128x128 tile, BK=64, XOR-swizzled LDS, sorted-xs gl_lds staging for A and B.
__global__ __launch_bounds__(256) void k_gemm(const unsigned short* __restrict__ xs,
                                              const unsigned short* __restrict__ wt,
                                              const float* __restrict__ b1,
                                              const float* __restrict__ rb1,
                                              const int* __restrict__ ws_i,
                                              unsigned short* __restrict__ h1) {
    __shared__ __align__(16) short As[128 * 64];   // 16 KB
    __shared__ __align__(16) short Bs[128 * 64];   // 16 KB
    int e, base, len;
    if (!chunk_lookup(ws_i + (WS_OFFS >> 2), blockIdx.x, 128, e, base, len)) return;
    int n0 = blockIdx.y * 128;
    int tid = threadIdx.x;
    int wave = tid >> 6, lane = tid & 63;
    int quad = lane >> 4, lr = lane & 15;
    int wm = (wave & 1) * 64, wn = (wave >> 1) * 64;

    f32x4 acc[4][4];
#pragma unroll
    for (int i = 0; i < 4; i++)
#pragma unroll
        for (int j = 0; j < 4; j++) acc[i][j] = (f32x4){0.f, 0.f, 0.f, 0.f};

    const unsigned short* Ag = xs + (size_t)base * 1024;
    const unsigned short* Bg = wt + (size_t)(e * 512 + n0) * 1024;

    // slot s = i*256 + wave*64 + lane; row r = s>>3; swizzled chunk cs = (s&7)^(r&7)
    const unsigned short* srcA[4];
    const unsigned short* srcB[4];
    int dst[4];
#pragma unroll
    for (int i = 0; i < 4; i++) {
        int s = i * 256 + wave * 64 + lane;
        int r = s >> 3, cs = (s & 7) ^ (r & 7);
        srcA[i] = Ag + (size_t)r * 1024 + cs * 8;
        srcB[i] = Bg + (size_t)r * 1024 + cs * 8;
        dst[i] = (i * 256 + wave * 64) * 8;
    }

    for (int kb = 0; kb < 16; kb++) {
        __syncthreads();   // LDS safe to overwrite
#pragma unroll
        for (int i = 0; i < 4; i++) {
            gl_lds16(srcA[i] + kb * 64, As + dst[i]);
            gl_lds16(srcB[i] + kb * 64, Bs + dst[i]);
        }
        __syncthreads();   // vmcnt(0) drain: DMA complete

        bf16x8 af[2][4], bfr[2][4];
#pragma unroll
        for (int im = 0; im < 4; im++) {
            int r = wm + im * 16 + lr;
#pragma unroll
            for (int kh = 0; kh < 2; kh++) {
                int q = kh * 4 + quad;
                af[kh][im] = *(const bf16x8*)(As + (r * 8 + (q ^ (r & 7))) * 8);
            }
        }
#pragma unroll
        for (int in = 0; in < 4; in++) {
            int r = wn + in * 16 + lr;
#pragma unroll
            for (int kh = 0; kh < 2; kh++) {
                int q = kh * 4 + quad;
                bfr[kh][in] = *(const bf16x8*)(Bs + (r * 8 + (q ^ (r & 7))) * 8);
            }
        }
#pragma unroll
        for (int kh = 0; kh < 2; kh++)
#pragma unroll
            for (int im = 0; im < 4; im++)
#pragma unroll
                for (int in = 0; in < 4; in++)
                    acc[im][in] = __builtin_amdgcn_mfma_f32_16x16x32_bf16(af[kh][im], bfr[kh][in], acc[im][in], 0, 0, 0);
    }

    // epilogue: + bias, relu, store bf16. C/D layout: col=lane&15, row=quad*4+reg.
#pragma unroll
    for (int in = 0; in < 4; in++) {
        int gcol = n0 + wn + in * 16 + lr;
        float bias = (gcol < 256) ? b1[e * 256 + gcol] : rb1[e * 256 + gcol - 256];
#pragma unroll
        for (int im = 0; im < 4; im++) {
#pragma unroll
            for (int v = 0; v < 4; v++) {
                int r = wm + im * 16 + quad * 4 + v;
                if (r < len) {
                    float val = fmaxf(acc[im][in][v] + bias, 0.f);
                    h1[(size_t)(base + r) * 512 + gcol] = f2bf(val);
                }
            }
        }
    }
}

// ---------------- kernel 4: MFMA tail — layers 2-4 + rot + masked scatter ----------------
__global__ __launch_bounds__(256) void k_tail(const unsigned short* __restrict__ h1,
                                              const int* __restrict__ ws_i,
                                              const unsigned short* __restrict__ w2t,
                                              const unsigned short* __restrict__ w3t,
                                              const unsigned short* __restrict__ w4t,
                                              const unsigned short* __restrict__ r2t,
                                              const float* __restrict__ b2,
                                              const float* __restrict__ b3,
                                              const float* __restrict__ b4,
                                              const float* __restrict__ rb2,
                                              const int* __restrict__ lengths,
                                              float* __restrict__ out) {
    __shared__ __align__(16) unsigned short h2s[4][16][64];
    __shared__ __align__(16) unsigned short h3s[4][16][32];

    int e, base, len;
    if (!chunk_lookup(ws_i + (WS_OFFS >> 2), blockIdx.x, 64, e, base, len)) return;
    int tid = threadIdx.x, wave = tid >> 6, lane = tid & 63;
    int quad = lane >> 4, lr = lane & 15;
    int m0 = wave * 16;

    const unsigned short* Ap = h1 + (size_t)(base + m0) * 512;

    f32x4 acc2[4];
#pragma unroll
    for (int t = 0; t < 4; t++) {
        float bb = b2[e * 64 + t * 16 + lr];
        acc2[t] = (f32x4){bb, bb, bb, bb};
    }
    f32x4 accr;
    { float bb = (lr < 3) ? rb2[e * 3 + lr] : 0.f; accr = (f32x4){bb, bb, bb, bb}; }

    const unsigned short* W2e = w2t + (size_t)e * 64 * 256;
    const unsigned short* R2e = r2t + (size_t)e * 16 * 256;
#pragma unroll
    for (int kk = 0; kk < 8; kk++) {
        int k0 = kk * 32;
        bf16x8 a = *(const bf16x8*)(Ap + lr * 512 + k0 + quad * 8);
#pragma unroll
        for (int t = 0; t < 4; t++) {
            bf16x8 b = *(const bf16x8*)(W2e + (t * 16 + lr) * 256 + k0 + quad * 8);
            acc2[t] = __builtin_amdgcn_mfma_f32_16x16x32_bf16(a, b, acc2[t], 0, 0, 0);
        }
        bf16x8 ar = *(const bf16x8*)(Ap + lr * 512 + 256 + k0 + quad * 8);
        bf16x8 br = *(const bf16x8*)(R2e + lr * 256 + k0 + quad * 8);
        accr = __builtin_amdgcn_mfma_f32_16x16x32_bf16(ar, br, accr, 0, 0, 0);
    }
#pragma unroll
    for (int t = 0; t < 4; t++)
#pragma unroll
        for (int v = 0; v < 4; v++)
            h2s[wave][quad * 4 + v][t * 16 + lr] = f2bf(fmaxf(acc2[t][v], 0.f));

    f32x4 acc3[2];
#pragma unroll
    for (int t = 0; t < 2; t++) {
        float bb = b3[e * 32 + t * 16 + lr];
        acc3[t] = (f32x4){bb, bb, bb, bb};
    }
    const unsigned short* W3e = w3t + (size_t)e * 32 * 64;
#pragma unroll
    for (int kk = 0; kk < 2; kk++) {
        int k0 = kk * 32;
        bf16x8 a = *(const bf16x8*)(&h2s[wave][lr][k0 + quad * 8]);
#pragma unroll
        for (int t = 0; t < 2; t++) {
            bf16x8 b = *(const bf16x8*)(W3e + (t * 16 + lr) * 64 + k0 + quad * 8);
            acc3[t] = __builtin_amdgcn_mfma_f32_16x16x32_bf16(a, b, acc3[t], 0, 0, 0);
        }
    }
#pragma unroll
    for (int t = 0; t < 2; t++)
#pragma unroll
        for (int v = 0; v < 4; v++)
            h3s[wave][quad * 4 + v][t * 16 + lr] = f2bf(fmaxf(acc3[t][v], 0.f));

    f32x4 acc4;
    { float bb = (lr < 14) ? b4[e * 14 + lr] : 0.f; acc4 = (f32x4){bb, bb, bb, bb}; }
    {
        bf16x8 a = *(const bf16x8*)(&h3s[wave][lr][quad * 8]);
        bf16x8 b = *(const bf16x8*)(w4t + ((size_t)e * 16 + lr) * 32 + quad * 8);
        acc4 = __builtin_amdgcn_mfma_f32_16x16x32_bf16(a, b, acc4, 0, 0, 0);
    }

    const int* perm = ws_i + (WS_PERM >> 2);
#pragma unroll
    for (int v = 0; v < 4; v++) {
        int t = m0 + quad * 4 + v;
        if (t < len) {
            int token = perm[base + t];
            int bi = token >> 9, ni = token & 511;
            int valid = ni < lengths[bi];
            if (lr < 14) out[(size_t)token * 17 + lr] = valid ? acc4[v] : EPSV;
            if (lr < 3)  out[(size_t)token * 17 + 14 + lr] = valid ? accr[v] : EPSV;
        }
    }
}

extern "C" void kernel_launch(void* const* d_in, const int* in_sizes, int n_in,
                              void* d_out, int out_size, void* d_ws, size_t ws_size,
                              hipStream_t stream) {
    (void)in_sizes; (void)n_in; (void)out_size; (void)ws_size;
    const float* nodes   = (const float*)d_in[0];
    const int*   sem     = (const int*)d_in[1];
    const int*   lengths = (const int*)d_in[2];
    const float* W1 = (const float*)d_in[3];
    const float* b1 = (const float*)d_in[4];
    const float* W2 = (const float*)d_in[5];
    const float* b2 = (const float*)d_in[6];
    const float* W3 = (const float*)d_in[7];
    const float* b3 = (const float*)d_in[8];
    const float* W4 = (const float*)d_in[9];
    const float* b4 = (const float*)d_in[10];
    const float* R1  = (const float*)d_in[11];
    const float* rb1 = (const float*)d_in[12];
    const float* R2  = (const float*)d_in[13];
    const float* rb2 = (const float*)d_in[14];
    float* out = (float*)d_out;

    char* ws = (char*)d_ws;
    int* ws_i = (int*)ws;
    unsigned short* xs  = (unsigned short*)(ws + WS_XS);
    unsigned short* wt  = (unsigned short*)(ws + WS_WT);
    unsigned short* h1  = (unsigned short*)(ws + WS_H1);
    unsigned short* w2t = (unsigned short*)(ws + WS_W2T);
    unsigned short* w3t = (unsigned short*)(ws + WS_W3T);
    unsigned short* w4t = (unsigned short*)(ws + WS_W4T);
    unsigned short* r2t = (unsigned short*)(ws + WS_R2T);

    hipLaunchKernelGGL(k_prep1, dim3(1088), dim3(256), 0, stream,
                       W1, R1, W2, W3, W4, R2, sem, wt, w2t, w3t, w4t, r2t, ws_i);
    hipLaunchKernelGGL(k_scatter, dim3(512), dim3(256), 0, stream, sem, nodes, ws_i, xs);
    hipLaunchKernelGGL(k_gemm, dim3(MAXC128, 4), dim3(256), 0, stream,
                       (const unsigned short*)xs, (const unsigned short*)wt, b1, rb1,
                       (const int*)ws_i, h1);
    hipLaunchKernelGGL(k_tail, dim3(MAXC64), dim3(256), 0, stream,
                       (const unsigned short*)h1, (const int*)ws_i,
                       (const unsigned short*)w2t, (const unsigned short*)w3t,
                       (const unsigned short*)w4t, (const unsigned short*)r2t,
                       b2, b3, b4, rb2, lengths, out);
}